// Round 1
// baseline (525.472 us; speedup 1.0000x reference)
//
#include <hip/hip_runtime.h>

// UpdateFunction: GRU-ish gated node update, B=64, N=1024, D=256.
//   z = sigmoid(m@w_z + h@u_z); r = sigmoid(m@w_r + h@u_r)
//   htil = tanh(m@w + (r*h)@u); out = mask * ((1-z)*h + z*htil)
// Strategy: bf16 MFMA (16x16x32). Stage A fuses z|r into one K=768,N=512 GEMM;
// Stage B is K=768,N=256 with r*h substituted into the h-region of LDS.

#define KTOT 768
#define ROWS 32   // rows per block; LDS X tile = 32*768*2B = 48 KB -> 3 blocks/CU

typedef __attribute__((ext_vector_type(8))) __bf16 bf16x8;
typedef __attribute__((ext_vector_type(4))) float f32x4;

__device__ __forceinline__ unsigned short f2bf(float f) {
    union { float f; unsigned u; } v; v.f = f;
    return (unsigned short)((v.u + 0x7FFFu + ((v.u >> 16) & 1u)) >> 16);  // RNE
}
__device__ __forceinline__ float bf2f(unsigned short b) {
    union { unsigned u; float f; } v; v.u = ((unsigned)b) << 16;
    return v.f;
}

// Pack weights into bf16, transposed: W1t[n][k] n in [0,512) (z cols | r cols),
// W2t[n][k] n in [0,256). k<512 -> w_* rows; k>=512 -> u_* rows.
__global__ void pack_weights(const float* __restrict__ wz, const float* __restrict__ uz,
                             const float* __restrict__ wr, const float* __restrict__ ur,
                             const float* __restrict__ w,  const float* __restrict__ u,
                             unsigned short* __restrict__ W1t, unsigned short* __restrict__ W2t)
{
    int id = blockIdx.x * 256 + threadIdx.x;   // grid covers exactly 768*768
    if (id < 512 * KTOT) {
        int n = id / KTOT, k = id - n * KTOT;
        float v;
        if (n < 256) v = (k < 512) ? wz[k * 256 + n] : uz[(k - 512) * 256 + n];
        else { int nn = n - 256; v = (k < 512) ? wr[k * 256 + nn] : ur[(k - 512) * 256 + nn]; }
        W1t[id] = f2bf(v);
    } else {
        int id2 = id - 512 * KTOT;
        int n = id2 / KTOT, k = id2 - n * KTOT;
        float v = (k < 512) ? w[k * 256 + n] : u[(k - 512) * 256 + n];
        W2t[id2] = f2bf(v);
    }
}

// XOR-swizzled LDS index: 16B blocks (8 bf16) permuted within groups of 8 blocks
// by row, so a quad's 16 A-frag lanes (consecutive rows, same k-block) hit 16
// distinct 16B bank groups -> conflict-free ds_read_b128.
__device__ __forceinline__ int sw_idx(int row, int k) {
    int kblk = k >> 3;
    int kb2 = (kblk & ~7) | ((kblk ^ row) & 7);
    return row * KTOT + kb2 * 8 + (k & 7);
}

__global__ __launch_bounds__(256, 2) void fused_gru(
    const float* __restrict__ h_in,   // [BN,256]
    const float* __restrict__ msg,    // [BN,512]
    const float* __restrict__ mask,   // [BN]
    const unsigned short* __restrict__ W1t,  // [512][768] bf16 bits
    const unsigned short* __restrict__ W2t,  // [256][768] bf16 bits
    float* __restrict__ out)          // [BN,256]
{
    __shared__ __align__(16) unsigned short Xs[ROWS * KTOT];  // 48 KB, swizzled
    __shared__ float maskS[ROWS];

    const int tid  = threadIdx.x;
    const int wave = tid >> 6;
    const int lane = tid & 63;
    const int p    = lane & 15;   // MFMA "column"/row-in-tile lane index
    const int q    = lane >> 4;   // quad: k-group for A/B, row-group for C/D
    const long r0  = (long)blockIdx.x * ROWS;

    // ---- Stage X = [m | h] into LDS as bf16 (swizzled) ----
    {
        const float4* m4 = (const float4*)(msg + r0 * 512);
        #pragma unroll
        for (int i = 0; i < 16; ++i) {           // 4096 float4 / 256 threads
            int f = tid + i * 256;
            int row = f >> 7, c4 = f & 127;      // 128 float4 per row
            float4 v = m4[f];
            int k = c4 * 4;
            unsigned short* d = &Xs[sw_idx(row, k)];
            unsigned long long pk =  (unsigned long long)f2bf(v.x)
                                  | ((unsigned long long)f2bf(v.y) << 16)
                                  | ((unsigned long long)f2bf(v.z) << 32)
                                  | ((unsigned long long)f2bf(v.w) << 48);
            *(unsigned long long*)d = pk;
        }
        const float4* h4 = (const float4*)(h_in + r0 * 256);
        #pragma unroll
        for (int i = 0; i < 8; ++i) {            // 2048 float4 / 256 threads
            int f = tid + i * 256;
            int row = f >> 6, c4 = f & 63;       // 64 float4 per row
            float4 v = h4[f];
            int k = 512 + c4 * 4;
            unsigned short* d = &Xs[sw_idx(row, k)];
            unsigned long long pk =  (unsigned long long)f2bf(v.x)
                                  | ((unsigned long long)f2bf(v.y) << 16)
                                  | ((unsigned long long)f2bf(v.z) << 32)
                                  | ((unsigned long long)f2bf(v.w) << 48);
            *(unsigned long long*)d = pk;
        }
        if (tid < ROWS) maskS[tid] = mask[r0 + tid];
    }
    __syncthreads();

    // Wave w owns output cols [w*64, w*64+64) of the 256 gate columns.
    // Per pass: 2 row-tiles x 4 col-tiles of 16x16, K-loop of 24 x 32.
    f32x4 acc[2][4];
    auto run_pass = [&](const unsigned short* __restrict__ Wt, int n0) {
        #pragma unroll
        for (int rt = 0; rt < 2; ++rt)
            #pragma unroll
            for (int c = 0; c < 4; ++c)
                #pragma unroll
                for (int i = 0; i < 4; ++i) acc[rt][c][i] = 0.f;
        for (int kk = 0; kk < 24; ++kk) {
            bf16x8 a0 = *(const bf16x8*)&Xs[sw_idx(p,      kk * 32 + q * 8)];
            bf16x8 a1 = *(const bf16x8*)&Xs[sw_idx(16 + p, kk * 32 + q * 8)];
            #pragma unroll
            for (int c = 0; c < 4; ++c) {
                bf16x8 b = *(const bf16x8*)(Wt + (n0 + c * 16 + p) * KTOT + kk * 32 + q * 8);
                acc[0][c] = __builtin_amdgcn_mfma_f32_16x16x32_bf16(a0, b, acc[0][c], 0, 0, 0);
                acc[1][c] = __builtin_amdgcn_mfma_f32_16x16x32_bf16(a1, b, acc[1][c], 0, 0, 0);
            }
        }
    };

    const int n0 = wave * 64;

    // ---- Pass Z: z = sigmoid(pre_z), kept in VGPRs ----
    float zs[2][4][4];
    run_pass(W1t, n0);            // z columns are W1t cols [0,256)
    #pragma unroll
    for (int rt = 0; rt < 2; ++rt)
        #pragma unroll
        for (int c = 0; c < 4; ++c)
            #pragma unroll
            for (int i = 0; i < 4; ++i)
                zs[rt][c][i] = 1.f / (1.f + __expf(-acc[rt][c][i]));

    // ---- Pass R: r = sigmoid(pre_r) ----
    float rs[2][4][4];
    run_pass(W1t, 256 + n0);      // r columns are W1t cols [256,512)
    #pragma unroll
    for (int rt = 0; rt < 2; ++rt)
        #pragma unroll
        for (int c = 0; c < 4; ++c)
            #pragma unroll
            for (int i = 0; i < 4; ++i)
                rs[rt][c][i] = 1.f / (1.f + __expf(-acc[rt][c][i]));

    // All waves done reading the h-region as A-frags; overwrite h -> r*h.
    __syncthreads();
    #pragma unroll
    for (int rt = 0; rt < 2; ++rt)
        #pragma unroll
        for (int c = 0; c < 4; ++c)
            #pragma unroll
            for (int i = 0; i < 4; ++i) {
                int row = rt * 16 + q * 4 + i;       // C/D layout: row = quad*4+reg
                int col = n0 + c * 16 + p;           //            col = lane&15
                unsigned short* ptr = &Xs[sw_idx(row, 512 + col)];
                float hv = bf2f(*ptr);
                *ptr = f2bf(rs[rt][c][i] * hv);
            }
    __syncthreads();

    // ---- Stage B: htil = tanh([m | r*h] @ W2t) ; fused epilogue ----
    run_pass(W2t, n0);
    #pragma unroll
    for (int rt = 0; rt < 2; ++rt)
        #pragma unroll
        for (int c = 0; c < 4; ++c)
            #pragma unroll
            for (int i = 0; i < 4; ++i) {
                int row  = rt * 16 + q * 4 + i;
                long grow = r0 + row;
                int col  = n0 + c * 16 + p;
                float pre = acc[rt][c][i];
                // tanh via exp, sign-safe
                float e  = __expf(-2.f * fabsf(pre));
                float t  = (1.f - e) / (1.f + e);
                float ht = (pre >= 0.f) ? t : -t;
                float zv = zs[rt][c][i];
                float hv = h_in[grow * 256 + col];
                out[grow * 256 + col] = maskS[row] * (hv + zv * (ht - hv));
            }
}

extern "C" void kernel_launch(void* const* d_in, const int* in_sizes, int n_in,
                              void* d_out, int out_size, void* d_ws, size_t ws_size,
                              hipStream_t stream) {
    const float* h_in = (const float*)d_in[0];   // node_state [64,1024,256]
    const float* msg  = (const float*)d_in[1];   // message    [64,1024,512]
    const float* mask = (const float*)d_in[2];   // mask       [64,1024]
    const float* wz   = (const float*)d_in[3];
    const float* uz   = (const float*)d_in[4];
    const float* wr   = (const float*)d_in[5];
    const float* ur   = (const float*)d_in[6];
    const float* w    = (const float*)d_in[7];
    const float* u    = (const float*)d_in[8];

    unsigned short* W1t = (unsigned short*)d_ws;           // 512*768 bf16
    unsigned short* W2t = W1t + 512 * KTOT;                // 256*768 bf16
    float* out = (float*)d_out;

    // 768*768 total packed elements / 256 threads = 2304 blocks (exact)
    pack_weights<<<2304, 256, 0, stream>>>(wz, uz, wr, ur, w, u, W1t, W2t);

    const int BN = 64 * 1024;
    fused_gru<<<BN / ROWS, 256, 0, stream>>>(h_in, msg, mask, W1t, W2t, out);
}

// Round 2
// 448.175 us; speedup vs baseline: 1.1725x; 1.1725x over previous
//
#include <hip/hip_runtime.h>

// UpdateFunction: GRU-ish gated node update, B=64, N=1024, D=256.
//   z = sigmoid(m@w_z + h@u_z); r = sigmoid(m@w_r + h@u_r)
//   htil = tanh(m@w + (r*h)@u); out = mask * ((1-z)*h + z*htil)
// bf16 MFMA 16x16x32. Weights pre-packed in FRAGMENT-MAJOR order so each
// B-fragment load is one coalesced 1KB global_load_dwordx4 (round-1 version
// scattered 64x16B per load -> TA/latency bound at 357us).

#define KTOT 768
#define ROWS 32            // LDS X tile = 32*768*2B = 48 KB -> 3 blocks/CU
#define TILE_SHORTS 12288  // one 16-col fragment tile: 24 kk * 64 lanes * 8 bf16

typedef __attribute__((ext_vector_type(8))) __bf16 bf16x8;
typedef __attribute__((ext_vector_type(8))) unsigned short ushort8;
typedef __attribute__((ext_vector_type(4))) float f32x4;

__device__ __forceinline__ unsigned short f2bf(float f) {
    union { float f; unsigned u; } v; v.f = f;
    return (unsigned short)((v.u + 0x7FFFu + ((v.u >> 16) & 1u)) >> 16);  // RNE
}
__device__ __forceinline__ float bf2f(unsigned short b) {
    union { unsigned u; float f; } v; v.u = ((unsigned)b) << 16;
    return v.f;
}

// ---------------------------------------------------------------------------
// Pack weights -> bf16, fragment-major.
// Output layout: for tile t (16 output cols), kk in [0,24), lane in [0,64):
//   chunk addr = ((t*24 + kk)*64 + lane)*8 shorts, 8 bf16 per chunk where
//   p=lane&15, q=lane>>4: element j = W[k = kk*32 + q*8 + j][n = t*16 + p].
// Grid: 48 blocks. b<16: W1 z-tiles (wz/uz); 16<=b<32: W1 r-tiles (wr/ur);
// b>=32: W2 tiles (w/u). 256 threads per block.
// ---------------------------------------------------------------------------
__global__ void pack_weights(const float* __restrict__ wz, const float* __restrict__ uz,
                             const float* __restrict__ wr, const float* __restrict__ ur,
                             const float* __restrict__ w,  const float* __restrict__ u,
                             unsigned short* __restrict__ W1t, unsigned short* __restrict__ W2t)
{
    __shared__ unsigned short buf[KTOT * 16];   // [k][nl], 24 KB
    const int tid = threadIdx.x;
    const int b   = blockIdx.x;

    const float* Wsrc; const float* Usrc; int ncb; unsigned short* outp;
    if (b < 16)      { Wsrc = wz; Usrc = uz; ncb = b * 16;        outp = W1t + b * TILE_SHORTS; }
    else if (b < 32) { Wsrc = wr; Usrc = ur; ncb = (b - 16) * 16; outp = W1t + b * TILE_SHORTS; }
    else             { Wsrc = w;  Usrc = u;  ncb = (b - 32) * 16; outp = W2t + (b - 32) * TILE_SHORTS; }

    // Coalesced read: 16 consecutive threads read 64B of one source row.
    #pragma unroll
    for (int i = 0; i < 48; ++i) {
        int id = tid + i * 256;            // 768*16 elements
        int k = id >> 4, nl = id & 15;
        float v = (k < 512) ? Wsrc[k * 256 + ncb + nl]
                            : Usrc[(k - 512) * 256 + ncb + nl];
        buf[id] = f2bf(v);
    }
    __syncthreads();

    // Write fragment chunks: 24*64 = 1536 chunks of 16B, contiguous stores.
    #pragma unroll
    for (int i = 0; i < 6; ++i) {
        int c = tid + i * 256;
        int kk = c >> 6, lane = c & 63;
        int p = lane & 15, q = lane >> 4;
        ushort8 pk;
        #pragma unroll
        for (int j = 0; j < 8; ++j)
            pk[j] = buf[(kk * 32 + q * 8 + j) * 16 + p];
        *(ushort8*)(outp + (unsigned)c * 8) = pk;
    }
}

// XOR-swizzled LDS index: 16B blocks permuted within groups of 8 by row.
__device__ __forceinline__ int sw_idx(int row, int k) {
    int kblk = k >> 3;
    int kb2 = (kblk & ~7) | ((kblk ^ row) & 7);
    return row * KTOT + kb2 * 8 + (k & 7);
}

__global__ __launch_bounds__(256, 3) void fused_gru(
    const float* __restrict__ h_in,   // [BN,256]
    const float* __restrict__ msg,    // [BN,512]
    const float* __restrict__ mask,   // [BN]
    const unsigned short* __restrict__ W1t,  // 32 fragment tiles (z|r)
    const unsigned short* __restrict__ W2t,  // 16 fragment tiles
    float* __restrict__ out)          // [BN,256]
{
    __shared__ __align__(16) unsigned short Xs[ROWS * KTOT];  // 48 KB, swizzled
    __shared__ float maskS[ROWS];

    const int tid  = threadIdx.x;
    const int wave = tid >> 6;
    const int lane = tid & 63;
    const int p    = lane & 15;
    const int q    = lane >> 4;
    const long r0  = (long)blockIdx.x * ROWS;

    // ---- Stage X = [m | h] into LDS as bf16 (swizzled) ----
    {
        const float4* m4 = (const float4*)(msg + r0 * 512);
        #pragma unroll
        for (int i = 0; i < 16; ++i) {           // 4096 float4 / 256 threads
            int f = tid + i * 256;
            int row = f >> 7, c4 = f & 127;
            float4 v = m4[f];
            unsigned short* d = &Xs[sw_idx(row, c4 * 4)];
            unsigned long long pk =  (unsigned long long)f2bf(v.x)
                                  | ((unsigned long long)f2bf(v.y) << 16)
                                  | ((unsigned long long)f2bf(v.z) << 32)
                                  | ((unsigned long long)f2bf(v.w) << 48);
            *(unsigned long long*)d = pk;
        }
        const float4* h4 = (const float4*)(h_in + r0 * 256);
        #pragma unroll
        for (int i = 0; i < 8; ++i) {            // 2048 float4 / 256 threads
            int f = tid + i * 256;
            int row = f >> 6, c4 = f & 63;
            float4 v = h4[f];
            unsigned short* d = &Xs[sw_idx(row, 512 + c4 * 4)];
            unsigned long long pk =  (unsigned long long)f2bf(v.x)
                                  | ((unsigned long long)f2bf(v.y) << 16)
                                  | ((unsigned long long)f2bf(v.z) << 32)
                                  | ((unsigned long long)f2bf(v.w) << 48);
            *(unsigned long long*)d = pk;
        }
        if (tid < ROWS) maskS[tid] = mask[r0 + tid];
    }
    __syncthreads();

    // Wave owns output cols [wave*64, wave*64+64): fragment tiles wave*4+c.
    f32x4 acc[2][4];
    auto run_pass = [&](const unsigned short* __restrict__ Wt, int tileBase) {
        #pragma unroll
        for (int rt = 0; rt < 2; ++rt)
            #pragma unroll
            for (int c = 0; c < 4; ++c)
                #pragma unroll
                for (int i = 0; i < 4; ++i) acc[rt][c][i] = 0.f;
        const unsigned short* w0 = Wt + (long)(tileBase + wave * 4) * TILE_SHORTS + lane * 8;
        for (int kk = 0; kk < 24; ++kk) {
            bf16x8 a0 = *(const bf16x8*)&Xs[sw_idx(p,      kk * 32 + q * 8)];
            bf16x8 a1 = *(const bf16x8*)&Xs[sw_idx(16 + p, kk * 32 + q * 8)];
            #pragma unroll
            for (int c = 0; c < 4; ++c) {
                bf16x8 b = *(const bf16x8*)(w0 + c * TILE_SHORTS + kk * 512);
                acc[0][c] = __builtin_amdgcn_mfma_f32_16x16x32_bf16(a0, b, acc[0][c], 0, 0, 0);
                acc[1][c] = __builtin_amdgcn_mfma_f32_16x16x32_bf16(a1, b, acc[1][c], 0, 0, 0);
            }
        }
    };

    // ---- Pass Z ----
    float zs[2][4][4];
    run_pass(W1t, 0);
    #pragma unroll
    for (int rt = 0; rt < 2; ++rt)
        #pragma unroll
        for (int c = 0; c < 4; ++c)
            #pragma unroll
            for (int i = 0; i < 4; ++i)
                zs[rt][c][i] = 1.f / (1.f + __expf(-acc[rt][c][i]));

    // ---- Pass R ----
    run_pass(W1t, 16);
    float rs[2][4][4];
    #pragma unroll
    for (int rt = 0; rt < 2; ++rt)
        #pragma unroll
        for (int c = 0; c < 4; ++c)
            #pragma unroll
            for (int i = 0; i < 4; ++i)
                rs[rt][c][i] = 1.f / (1.f + __expf(-acc[rt][c][i]));

    // All waves done reading h as A-frags; overwrite h -> r*h, cache h in regs.
    __syncthreads();
    float hs[2][4][4];
    #pragma unroll
    for (int rt = 0; rt < 2; ++rt)
        #pragma unroll
        for (int c = 0; c < 4; ++c)
            #pragma unroll
            for (int i = 0; i < 4; ++i) {
                int row = rt * 16 + q * 4 + i;       // C/D: row = quad*4+reg
                int col = wave * 64 + c * 16 + p;    //      col = lane&15
                unsigned short* ptr = &Xs[sw_idx(row, 512 + col)];
                float hv = bf2f(*ptr);
                hs[rt][c][i] = hv;
                *ptr = f2bf(rs[rt][c][i] * hv);
            }
    __syncthreads();

    // ---- Pass B + fused epilogue ----
    run_pass(W2t, 0);
    #pragma unroll
    for (int rt = 0; rt < 2; ++rt)
        #pragma unroll
        for (int c = 0; c < 4; ++c)
            #pragma unroll
            for (int i = 0; i < 4; ++i) {
                int row  = rt * 16 + q * 4 + i;
                long grow = r0 + row;
                int col  = wave * 64 + c * 16 + p;
                float pre = acc[rt][c][i];
                float e  = __expf(-2.f * fabsf(pre));
                float t  = (1.f - e) / (1.f + e);
                float ht = (pre >= 0.f) ? t : -t;
                float zv = zs[rt][c][i];
                float hv = hs[rt][c][i];
                out[grow * 256 + col] = maskS[row] * (hv + zv * (ht - hv));
            }
}

extern "C" void kernel_launch(void* const* d_in, const int* in_sizes, int n_in,
                              void* d_out, int out_size, void* d_ws, size_t ws_size,
                              hipStream_t stream) {
    const float* h_in = (const float*)d_in[0];   // node_state [64,1024,256]
    const float* msg  = (const float*)d_in[1];   // message    [64,1024,512]
    const float* mask = (const float*)d_in[2];   // mask       [64,1024]
    const float* wz   = (const float*)d_in[3];
    const float* uz   = (const float*)d_in[4];
    const float* wr   = (const float*)d_in[5];
    const float* ur   = (const float*)d_in[6];
    const float* w    = (const float*)d_in[7];
    const float* u    = (const float*)d_in[8];

    unsigned short* W1t = (unsigned short*)d_ws;           // 32 tiles
    unsigned short* W2t = W1t + 32 * TILE_SHORTS;          // 16 tiles
    float* out = (float*)d_out;

    pack_weights<<<48, 256, 0, stream>>>(wz, uz, wr, ur, w, u, W1t, W2t);

    const int BN = 64 * 1024;
    fused_gru<<<BN / ROWS, 256, 0, stream>>>(h_in, msg, mask, W1t, W2t, out);
}

// Round 3
// 417.853 us; speedup vs baseline: 1.2576x; 1.0726x over previous
//
#include <hip/hip_runtime.h>

// UpdateFunction: GRU-ish gated node update, B=64, N=1024, D=256.
//   z = sigmoid(m@w_z + h@u_z); r = sigmoid(m@w_r + h@u_r)
//   htil = tanh(m@w + (r*h)@u); out = mask * ((1-z)*h + z*htil)
// bf16 MFMA 16x16x32, fragment-major pre-packed weights (1KB coalesced B-loads).
// R3: Z+R fused into one K-loop (shared A-frags, 16 indep MFMAs/iter) +
// explicit depth-1 software pipeline, loop fully unrolled. Round-2 was
// latency-exposed every 8 MFMAs (MfmaUtil 11%).

#define KTOT 768
#define ROWS 32            // LDS X tile = 32*768*2B = 48 KB -> 3 blocks/CU
#define TILE_SHORTS 12288  // one 16-col fragment tile: 24 kk * 64 lanes * 8 bf16

typedef __attribute__((ext_vector_type(8))) __bf16 bf16x8;
typedef __attribute__((ext_vector_type(8))) unsigned short ushort8;
typedef __attribute__((ext_vector_type(4))) float f32x4;

#define MFMA(a, b, c) __builtin_amdgcn_mfma_f32_16x16x32_bf16((a), (b), (c), 0, 0, 0)

__device__ __forceinline__ unsigned short f2bf(float f) {
    union { float f; unsigned u; } v; v.f = f;
    return (unsigned short)((v.u + 0x7FFFu + ((v.u >> 16) & 1u)) >> 16);  // RNE
}
__device__ __forceinline__ float bf2f(unsigned short b) {
    union { unsigned u; float f; } v; v.u = ((unsigned)b) << 16;
    return v.f;
}

// ---------------------------------------------------------------------------
// Pack weights -> bf16, fragment-major.
// For tile t (16 output cols), kk in [0,24), lane in [0,64):
//   chunk addr = ((t*24 + kk)*64 + lane)*8 shorts; p=lane&15, q=lane>>4:
//   element j = W[k = kk*32 + q*8 + j][n = t*16 + p].
// ---------------------------------------------------------------------------
__global__ void pack_weights(const float* __restrict__ wz, const float* __restrict__ uz,
                             const float* __restrict__ wr, const float* __restrict__ ur,
                             const float* __restrict__ w,  const float* __restrict__ u,
                             unsigned short* __restrict__ W1t, unsigned short* __restrict__ W2t)
{
    __shared__ unsigned short buf[KTOT * 16];   // [k][nl], 24 KB
    const int tid = threadIdx.x;
    const int b   = blockIdx.x;

    const float* Wsrc; const float* Usrc; int ncb; unsigned short* outp;
    if (b < 16)      { Wsrc = wz; Usrc = uz; ncb = b * 16;        outp = W1t + b * TILE_SHORTS; }
    else if (b < 32) { Wsrc = wr; Usrc = ur; ncb = (b - 16) * 16; outp = W1t + b * TILE_SHORTS; }
    else             { Wsrc = w;  Usrc = u;  ncb = (b - 32) * 16; outp = W2t + (b - 32) * TILE_SHORTS; }

    #pragma unroll
    for (int i = 0; i < 48; ++i) {
        int id = tid + i * 256;            // 768*16 elements
        int k = id >> 4, nl = id & 15;
        float v = (k < 512) ? Wsrc[k * 256 + ncb + nl]
                            : Usrc[(k - 512) * 256 + ncb + nl];
        buf[id] = f2bf(v);
    }
    __syncthreads();

    #pragma unroll
    for (int i = 0; i < 6; ++i) {
        int c = tid + i * 256;
        int kk = c >> 6, lane = c & 63;
        int p = lane & 15, q = lane >> 4;
        ushort8 pk;
        #pragma unroll
        for (int j = 0; j < 8; ++j)
            pk[j] = buf[(kk * 32 + q * 8 + j) * 16 + p];
        *(ushort8*)(outp + (unsigned)c * 8) = pk;
    }
}

// XOR-swizzled LDS index: 16B blocks permuted within groups of 8 by row.
__device__ __forceinline__ int sw_idx(int row, int k) {
    int kblk = k >> 3;
    int kb2 = (kblk & ~7) | ((kblk ^ row) & 7);
    return row * KTOT + kb2 * 8 + (k & 7);
}

__global__ __launch_bounds__(256, 3) void fused_gru(
    const float* __restrict__ h_in,   // [BN,256]
    const float* __restrict__ msg,    // [BN,512]
    const float* __restrict__ mask,   // [BN]
    const unsigned short* __restrict__ W1t,  // 32 fragment tiles (z|r)
    const unsigned short* __restrict__ W2t,  // 16 fragment tiles
    float* __restrict__ out)          // [BN,256]
{
    __shared__ __align__(16) unsigned short Xs[ROWS * KTOT];  // 48 KB, swizzled
    __shared__ float maskS[ROWS];

    const int tid  = threadIdx.x;
    const int wave = tid >> 6;
    const int lane = tid & 63;
    const int p    = lane & 15;
    const int q    = lane >> 4;
    const long r0  = (long)blockIdx.x * ROWS;

    // ---- Stage X = [m | h] into LDS as bf16 (swizzled) ----
    {
        const float4* m4 = (const float4*)(msg + r0 * 512);
        #pragma unroll
        for (int i = 0; i < 16; ++i) {           // 4096 float4 / 256 threads
            int f = tid + i * 256;
            int row = f >> 7, c4 = f & 127;
            float4 v = m4[f];
            unsigned short* d = &Xs[sw_idx(row, c4 * 4)];
            unsigned long long pk =  (unsigned long long)f2bf(v.x)
                                  | ((unsigned long long)f2bf(v.y) << 16)
                                  | ((unsigned long long)f2bf(v.z) << 32)
                                  | ((unsigned long long)f2bf(v.w) << 48);
            *(unsigned long long*)d = pk;
        }
        const float4* h4 = (const float4*)(h_in + r0 * 256);
        #pragma unroll
        for (int i = 0; i < 8; ++i) {            // 2048 float4 / 256 threads
            int f = tid + i * 256;
            int row = f >> 6, c4 = f & 63;
            float4 v = h4[f];
            unsigned short* d = &Xs[sw_idx(row, 512 + c4 * 4)];
            unsigned long long pk =  (unsigned long long)f2bf(v.x)
                                  | ((unsigned long long)f2bf(v.y) << 16)
                                  | ((unsigned long long)f2bf(v.z) << 32)
                                  | ((unsigned long long)f2bf(v.w) << 48);
            *(unsigned long long*)d = pk;
        }
        if (tid < ROWS) maskS[tid] = mask[r0 + tid];
    }
    __syncthreads();

    // Wave owns output cols [wave*64, wave*64+64): fragment tiles wave*4+c.
    const unsigned short* wzp = W1t + (long)(wave * 4) * TILE_SHORTS + lane * 8;
    const unsigned short* wrp = wzp + 16L * TILE_SHORTS;
    const unsigned short* wbp = W2t + (long)(wave * 4) * TILE_SHORTS + lane * 8;

    // ---- Fused Z+R pass: one K-loop, 16 indep MFMAs/iter, depth-1 pipeline ----
    f32x4 accz[2][4], accr[2][4];
    #pragma unroll
    for (int rt = 0; rt < 2; ++rt)
        #pragma unroll
        for (int c = 0; c < 4; ++c)
            #pragma unroll
            for (int i = 0; i < 4; ++i) { accz[rt][c][i] = 0.f; accr[rt][c][i] = 0.f; }

    {
        bf16x8 a0 = *(const bf16x8*)&Xs[sw_idx(p,      q * 8)];
        bf16x8 a1 = *(const bf16x8*)&Xs[sw_idx(16 + p, q * 8)];
        bf16x8 zb[4];
        #pragma unroll
        for (int c = 0; c < 4; ++c) zb[c] = *(const bf16x8*)(wzp + c * TILE_SHORTS);

        #pragma unroll
        for (int kk = 0; kk < 24; ++kk) {
            bf16x8 rb[4];
            #pragma unroll
            for (int c = 0; c < 4; ++c)
                rb[c] = *(const bf16x8*)(wrp + c * TILE_SHORTS + kk * 512);
            // z-MFMAs (cover r-frag load latency)
            #pragma unroll
            for (int c = 0; c < 4; ++c) {
                accz[0][c] = MFMA(a0, zb[c], accz[0][c]);
                accz[1][c] = MFMA(a1, zb[c], accz[1][c]);
            }
            bf16x8 na0, na1, nzb[4];
            if (kk < 23) {
                #pragma unroll
                for (int c = 0; c < 4; ++c)
                    nzb[c] = *(const bf16x8*)(wzp + c * TILE_SHORTS + (kk + 1) * 512);
                na0 = *(const bf16x8*)&Xs[sw_idx(p,      (kk + 1) * 32 + q * 8)];
                na1 = *(const bf16x8*)&Xs[sw_idx(16 + p, (kk + 1) * 32 + q * 8)];
            }
            // r-MFMAs (cover next-iter z/A load latency)
            #pragma unroll
            for (int c = 0; c < 4; ++c) {
                accr[0][c] = MFMA(a0, rb[c], accr[0][c]);
                accr[1][c] = MFMA(a1, rb[c], accr[1][c]);
            }
            if (kk < 23) {
                a0 = na0; a1 = na1;
                #pragma unroll
                for (int c = 0; c < 4; ++c) zb[c] = nzb[c];
            }
        }
    }

    float zs[2][4][4], rs[2][4][4];
    #pragma unroll
    for (int rt = 0; rt < 2; ++rt)
        #pragma unroll
        for (int c = 0; c < 4; ++c)
            #pragma unroll
            for (int i = 0; i < 4; ++i) {
                zs[rt][c][i] = 1.f / (1.f + __expf(-accz[rt][c][i]));
                rs[rt][c][i] = 1.f / (1.f + __expf(-accr[rt][c][i]));
            }

    // All waves done reading h as A-frags; overwrite h -> r*h, cache h in regs.
    __syncthreads();
    float hs[2][4][4];
    #pragma unroll
    for (int rt = 0; rt < 2; ++rt)
        #pragma unroll
        for (int c = 0; c < 4; ++c)
            #pragma unroll
            for (int i = 0; i < 4; ++i) {
                int row = rt * 16 + q * 4 + i;       // C/D: row = quad*4+reg
                int col = wave * 64 + c * 16 + p;    //      col = lane&15
                unsigned short* ptr = &Xs[sw_idx(row, 512 + col)];
                float hv = bf2f(*ptr);
                hs[rt][c][i] = hv;
                *ptr = f2bf(rs[rt][c][i] * hv);
            }
    __syncthreads();

    // ---- Pass B: htil = tanh([m | r*h] @ W2t), pipelined ----
    f32x4 acc[2][4];
    #pragma unroll
    for (int rt = 0; rt < 2; ++rt)
        #pragma unroll
        for (int c = 0; c < 4; ++c)
            #pragma unroll
            for (int i = 0; i < 4; ++i) acc[rt][c][i] = 0.f;

    {
        bf16x8 a0 = *(const bf16x8*)&Xs[sw_idx(p,      q * 8)];
        bf16x8 a1 = *(const bf16x8*)&Xs[sw_idx(16 + p, q * 8)];
        bf16x8 bb[4];
        #pragma unroll
        for (int c = 0; c < 4; ++c) bb[c] = *(const bf16x8*)(wbp + c * TILE_SHORTS);

        #pragma unroll
        for (int kk = 0; kk < 24; ++kk) {
            bf16x8 na0, na1, nbb[4];
            if (kk < 23) {
                #pragma unroll
                for (int c = 0; c < 4; ++c)
                    nbb[c] = *(const bf16x8*)(wbp + c * TILE_SHORTS + (kk + 1) * 512);
                na0 = *(const bf16x8*)&Xs[sw_idx(p,      (kk + 1) * 32 + q * 8)];
                na1 = *(const bf16x8*)&Xs[sw_idx(16 + p, (kk + 1) * 32 + q * 8)];
            }
            #pragma unroll
            for (int c = 0; c < 4; ++c) {
                acc[0][c] = MFMA(a0, bb[c], acc[0][c]);
                acc[1][c] = MFMA(a1, bb[c], acc[1][c]);
            }
            if (kk < 23) {
                a0 = na0; a1 = na1;
                #pragma unroll
                for (int c = 0; c < 4; ++c) bb[c] = nbb[c];
            }
        }
    }

    // ---- Fused epilogue ----
    #pragma unroll
    for (int rt = 0; rt < 2; ++rt)
        #pragma unroll
        for (int c = 0; c < 4; ++c)
            #pragma unroll
            for (int i = 0; i < 4; ++i) {
                int row  = rt * 16 + q * 4 + i;
                long grow = r0 + row;
                int col  = wave * 64 + c * 16 + p;
                float pre = acc[rt][c][i];
                float e  = __expf(-2.f * fabsf(pre));
                float t  = (1.f - e) / (1.f + e);
                float ht = (pre >= 0.f) ? t : -t;
                float zv = zs[rt][c][i];
                float hv = hs[rt][c][i];
                out[grow * 256 + col] = maskS[row] * (hv + zv * (ht - hv));
            }
}

extern "C" void kernel_launch(void* const* d_in, const int* in_sizes, int n_in,
                              void* d_out, int out_size, void* d_ws, size_t ws_size,
                              hipStream_t stream) {
    const float* h_in = (const float*)d_in[0];   // node_state [64,1024,256]
    const float* msg  = (const float*)d_in[1];   // message    [64,1024,512]
    const float* mask = (const float*)d_in[2];   // mask       [64,1024]
    const float* wz   = (const float*)d_in[3];
    const float* uz   = (const float*)d_in[4];
    const float* wr   = (const float*)d_in[5];
    const float* ur   = (const float*)d_in[6];
    const float* w    = (const float*)d_in[7];
    const float* u    = (const float*)d_in[8];

    unsigned short* W1t = (unsigned short*)d_ws;           // 32 tiles
    unsigned short* W2t = W1t + 32 * TILE_SHORTS;          // 16 tiles
    float* out = (float*)d_out;

    pack_weights<<<48, 256, 0, stream>>>(wz, uz, wr, ur, w, u, W1t, W2t);

    const int BN = 64 * 1024;
    fused_gru<<<BN / ROWS, 256, 0, stream>>>(h_in, msg, mask, W1t, W2t, out);
}